// Round 14
// baseline (192.512 us; speedup 1.0000x reference)
//
#include <hip/hip_runtime.h>
#include <stdint.h>

typedef __attribute__((ext_vector_type(8))) short short8;
typedef __attribute__((ext_vector_type(4))) float f32x4;
typedef __attribute__((ext_vector_type(16))) float f32x16;
typedef __attribute__((ext_vector_type(4))) unsigned u32x4;

#define DEVINL __device__ __forceinline__

DEVINL unsigned short f2bf(float f) {
  unsigned u = __float_as_uint(f);
  u = (u + 0x7FFFu + ((u >> 16) & 1u)) >> 16;
  return (unsigned short)u;
}

DEVINL void gload_lds16(const void* g, void* lds) {
  __builtin_amdgcn_global_load_lds(
      (const __attribute__((address_space(1))) unsigned int*)g,
      (__attribute__((address_space(3))) unsigned int*)lds, 16, 0, 0);
}

DEVINL float fexp2(float x) {
  float r;
  asm("v_exp_f32 %0, %1" : "=v"(r) : "v"(x));
  return r;
}

DEVINL unsigned cvtpk(float lo, float hi) {
  unsigned r;
  asm("v_cvt_pk_bf16_f32 %0, %1, %2" : "=v"(r) : "v"(lo), "v"(hi));
  return r;
}

DEVINL void pl32swap(unsigned& a, unsigned& b) {
  asm("v_permlane32_swap_b32 %0, %1" : "+v"(a), "+v"(b));
}

// ---------------- fused prep: weight cvts + W1T + WoT + bias folds ----------------
// grid 2560 x 256. bid<1024: bf16 cvt of W2/Wq/Wk/Wv; else W1T/WoT/bias-folds.
__global__ void prep_all(const float* __restrict__ W2, const float* __restrict__ Wq,
                         const float* __restrict__ Wk, const float* __restrict__ Wv,
                         const float* __restrict__ W1, const float* __restrict__ Wo,
                         const float* __restrict__ b2,
                         unsigned short* __restrict__ W2B, unsigned short* __restrict__ WqB,
                         unsigned short* __restrict__ WkB, unsigned short* __restrict__ WvB,
                         unsigned short* __restrict__ W1T, unsigned short* __restrict__ WoT,
                         float* __restrict__ bqf, float* __restrict__ bkf) {
  const int tid = threadIdx.x;
  int bid = blockIdx.x;
  if (bid < 1024) {
    const int a = bid >> 8;
    const int i = (bid & 255) * 256 + tid;
    const float* src = (a == 0) ? W2 : (a == 1) ? Wq : (a == 2) ? Wk : Wv;
    unsigned short* dst = (a == 0) ? W2B : (a == 1) ? WqB : (a == 2) ? WkB : WvB;
    const float scale = (a == 1) ? 0.18033688f : 1.0f;  // Wq: 1/sqrt(64) * log2(e)
    float4 v = ((const float4*)src)[i];
    ushort4 o;
    o.x = f2bf(v.x * scale); o.y = f2bf(v.y * scale);
    o.z = f2bf(v.z * scale); o.w = f2bf(v.w * scale);
    ((ushort4*)dst)[i] = o;
    return;
  }
  bid -= 1024;
  if (bid < 256) {                       // W1T[n][k] = W1[k][n], 512x128
    int idx = bid * 256 + tid;
    int n = idx >> 7, k = idx & 127;
    W1T[idx] = f2bf(W1[(size_t)k * 512 + n]);
  } else if (bid < 1280) {               // WoT[d][h*64+e] = Wo[h][d][e]
    int idx = (bid - 256) * 256 + tid;
    int d = idx >> 9, j = idx & 511, h = j >> 6, e = j & 63;
    WoT[idx] = f2bf(Wo[(size_t)h * 32768 + (size_t)d * 64 + e]);
  } else {                               // bias folds from f32 weights
    int rid = (bid - 1280) * 4 + (tid >> 6);
    int l = tid & 63;
    int e = rid & 511, which = rid >> 9;
    const float* W = which ? Wk : Wq;
    float scale = which ? 1.0f : 0.18033688f;
    float acc = 0.f;
#pragma unroll
    for (int j = 0; j < 8; ++j)
      acc += b2[l * 8 + j] * W[(size_t)e * 512 + l * 8 + j];
    acc *= scale;
#pragma unroll
    for (int off = 1; off < 64; off <<= 1) acc += __shfl_xor(acc, off, 64);
    if (l == 0) (which ? bkf : bqf)[e] = acc;
  }
}

// x1,x2 -> Xb[32768][128]; r -> Rb. grid 12288 x 256.
__global__ void cvt_all(const float* __restrict__ x1, const float* __restrict__ x2,
                        const float* __restrict__ r,
                        unsigned short* __restrict__ Xb, unsigned short* __restrict__ Rb) {
  const int bid = blockIdx.x, tid = threadIdx.x;
  const float* src;
  unsigned short* dst;
  int i;
  if (bid < 2048)      { src = x1; dst = Xb;           i = bid * 256 + tid; }
  else if (bid < 4096) { src = x2; dst = Xb + 2097152; i = (bid - 2048) * 256 + tid; }
  else                 { src = r;  dst = Rb;           i = (bid - 4096) * 256 + tid; }
  float4 v = ((const float4*)src)[i];
  ushort4 o;
  o.x = f2bf(v.x); o.y = f2bf(v.y); o.z = f2bf(v.z); o.w = f2bf(v.w);
  ((ushort4*)dst)[i] = o;
}

// ---------------- GEMM: C[M,N] = A[M,K]*Bt[N,K]^T, BK=64, pipelined single-buffer ----------------
// z-batched (up to 3 problems, per-z N and grid-cols nx; shared K). grid (nwg, 1, nz).
template <bool RELU, typename TOut>
__global__ __launch_bounds__(256) void gemm64(
    const unsigned short* A0, const unsigned short* B0, const float* bias0, TOut* C0, int N0, int nx0,
    const unsigned short* A1, const unsigned short* B1, const float* bias1, TOut* C1, int N1, int nx1,
    const unsigned short* A2, const unsigned short* B2, const float* bias2, TOut* C2, int N2, int nx2,
    int K) {
  __shared__ __align__(16) char smem[32768];
  unsigned short* As = (unsigned short*)smem;
  unsigned short* Bs = (unsigned short*)(smem + 16384);

  const int z = blockIdx.z;
  const unsigned short* A = (z == 0) ? A0 : (z == 1) ? A1 : A2;
  const unsigned short* Bt = (z == 0) ? B0 : (z == 1) ? B1 : B2;
  const float* bias = (z == 0) ? bias0 : (z == 1) ? bias1 : bias2;
  TOut* C = (z == 0) ? C0 : (z == 1) ? C1 : C2;
  const int N = (z == 0) ? N0 : (z == 1) ? N1 : N2;
  const int nx = (z == 0) ? nx0 : (z == 1) ? nx1 : nx2;

  // XCD-chunked block swizzle
  int id = blockIdx.x;
  const int nwg = gridDim.x;
  if ((nwg & 7) == 0) id = (id & 7) * (nwg >> 3) + (id >> 3);
  const int n0 = (id % nx) * 128, m0 = (id / nx) * 128;

  const int tid = threadIdx.x, w = tid >> 6, l = tid & 63;
  const int wm = w >> 1, wn = w & 1;
  const int lr = l & 15, lg = l >> 4;
  const int nt = K >> 6;

  f32x4 zero4 = {0.f, 0.f, 0.f, 0.f};
  f32x4 acc[4][4];
#pragma unroll
  for (int i = 0; i < 4; ++i)
#pragma unroll
    for (int j = 0; j < 4; ++j) acc[i][j] = zero4;

  auto STAGE = [&](int t) {
#pragma unroll
    for (int i = 0; i < 4; ++i) {
      const int c = i * 256 + tid;                 // 16B chunk id, 0..1023
      const int row = c >> 3, ch = c & 7;
      const int sl = (ch ^ (row & 7)) * 8;         // pre-swizzled global source
      gload_lds16(A + (size_t)(m0 + row) * K + t * 64 + sl, (char*)As + c * 16);
      gload_lds16(Bt + (size_t)(n0 + row) * K + t * 64 + sl, (char*)Bs + c * 16);
    }
  };

  STAGE(0);
  for (int t = 0; t < nt; ++t) {
    asm volatile("s_waitcnt vmcnt(0)" ::: "memory");   // tile t landed
    __builtin_amdgcn_s_barrier();
    // ---- drain LDS into register frags (frees the buffer) ----
    short8 af[2][4], bfr[2][4];
#pragma unroll
    for (int kk = 0; kk < 2; ++kk) {
#pragma unroll
      for (int mi = 0; mi < 4; ++mi) {
        const int row = wm * 64 + mi * 16 + lr;
        af[kk][mi] = *(const short8*)((const char*)As + row * 128 + (((kk * 4 + lg) ^ (row & 7)) * 16));
      }
#pragma unroll
      for (int ni = 0; ni < 4; ++ni) {
        const int row = wn * 64 + ni * 16 + lr;
        bfr[kk][ni] = *(const short8*)((const char*)Bs + row * 128 + (((kk * 4 + lg) ^ (row & 7)) * 16));
      }
    }
    asm volatile("s_waitcnt lgkmcnt(0)" ::: "memory");
    __builtin_amdgcn_s_barrier();                      // all waves done reading LDS
    if (t + 1 < nt) STAGE(t + 1);                      // overwrite under the MFMAs
    __builtin_amdgcn_sched_barrier(0);
#pragma unroll
    for (int kk = 0; kk < 2; ++kk)
#pragma unroll
      for (int mi = 0; mi < 4; ++mi)
#pragma unroll
        for (int ni = 0; ni < 4; ++ni)
          acc[mi][ni] = __builtin_amdgcn_mfma_f32_16x16x32_bf16(af[kk][mi], bfr[kk][ni], acc[mi][ni], 0, 0, 0);
  }

#pragma unroll
  for (int ni = 0; ni < 4; ++ni) {
    const int col = n0 + wn * 64 + ni * 16 + lr;
    const float bv = bias ? bias[col] : 0.f;
#pragma unroll
    for (int mi = 0; mi < 4; ++mi) {
      const int row = m0 + wm * 64 + mi * 16 + lg * 4;
#pragma unroll
      for (int r = 0; r < 4; ++r) {
        float v = acc[mi][ni][r] + bv;
        if (RELU) v = fmaxf(v, 0.f);
        if constexpr (sizeof(TOut) == 2)
          C[(size_t)(row + r) * N + col] = (TOut)f2bf(v);
        else
          C[(size_t)(row + r) * N + col] = v;
      }
    }
  }
}

// ---------------- flash attention: dbuf 128-key tiles, swapped 32x32, defer-max ----------------
// VT2: [512 e_g][16384 n_g] bf16 (e_g = h*64+e, n_g = b*2048+n)
// Per stage: K 128x64 (16KB, row-swizzled) + V^T 64x128 (16KB, row-swizzled).
DEVINL void stage_kv2(const unsigned short* Kp, const unsigned short* Vp,
                      char* kb, char* vb, int tid, int k0) {
#pragma unroll
  for (int i = 0; i < 2; ++i) {
    const int c = i * 512 + tid;                  // 16B chunk, 0..1023
    const int krow = c >> 3, kcs = c & 7;
    gload_lds16(Kp + (size_t)(k0 + krow) * 512 + ((kcs ^ (krow & 7)) * 8), kb + c * 16);
    const int e = c >> 4, ck = c & 15;
    gload_lds16(Vp + (size_t)e * 16384 + k0 + ((ck ^ (e & 7)) * 8), vb + c * 16);
  }
}

__global__ __launch_bounds__(512) void attn_sw(
    const unsigned short* __restrict__ Q, const unsigned short* __restrict__ Kh,
    const unsigned short* __restrict__ VT2, unsigned short* __restrict__ O) {
  const int bh = blockIdx.x, b = bh >> 3, h = bh & 7;
  const int q0 = blockIdx.y * 256;
  const int tid = threadIdx.x, w = tid >> 6, l = tid & 63;
  const int lq = l & 31, hi = l >> 5;
  const size_t baseBH = (size_t)b * 2048 * 512 + (size_t)h * 64;

  __shared__ __align__(16) char smem[65536];  // dbuf: [K 16K | V 16K] x2; eps overlays

  const unsigned short* Kp = Kh + baseBH;
  const unsigned short* Vp = VT2 + (size_t)(h * 64) * 16384 + (size_t)b * 2048;

  // ---- Q direct to registers ----
  short8 qf[4];
  {
    const unsigned short* qp = Q + baseBH + (size_t)(q0 + w * 32 + lq) * 512 + hi * 8;
#pragma unroll
    for (int kc = 0; kc < 4; ++kc) qf[kc] = *(const short8*)(qp + kc * 16);
  }

  f32x16 ot0 = {0,0,0,0,0,0,0,0,0,0,0,0,0,0,0,0};
  f32x16 ot1 = {0,0,0,0,0,0,0,0,0,0,0,0,0,0,0,0};
  float m_run = -1e30f, l_run = 0.f;
  const int xs = (lq & 7);

  stage_kv2(Kp, Vp, smem, smem + 16384, tid, 0);

  for (int t = 0; t < 16; ++t) {
    asm volatile("s_waitcnt vmcnt(0)" ::: "memory");   // tile t landed (own loads)
    __builtin_amdgcn_s_barrier();                      // all waves' loads landed
    const int cur = t & 1;
    if (t < 15)
      stage_kv2(Kp, Vp, smem + (cur ^ 1) * 32768, smem + (cur ^ 1) * 32768 + 16384,
                tid, (t + 1) * 128);
    const char* klc = smem + cur * 32768;
    const char* vtc = klc + 16384;

#pragma unroll
    for (int h2 = 0; h2 < 2; ++h2) {
      // ---- S^T = K Q^T (64-key half) ----
      f32x16 st0 = {0,0,0,0,0,0,0,0,0,0,0,0,0,0,0,0};
      f32x16 st1 = {0,0,0,0,0,0,0,0,0,0,0,0,0,0,0,0};
      __builtin_amdgcn_s_setprio(1);
#pragma unroll
      for (int kc = 0; kc < 4; ++kc) {
        const int sl = ((kc * 2 + hi) ^ xs) * 16;
        short8 kf0 = *(const short8*)(klc + (h2 * 64 + lq) * 128 + sl);
        short8 kf1 = *(const short8*)(klc + (h2 * 64 + 32 + lq) * 128 + sl);
        st0 = __builtin_amdgcn_mfma_f32_32x32x16_bf16(kf0, qf[kc], st0, 0, 0, 0);
        st1 = __builtin_amdgcn_mfma_f32_32x32x16_bf16(kf1, qf[kc], st1, 0, 0, 0);
      }
      __builtin_amdgcn_s_setprio(0);

      // ---- online softmax (log2 domain), per-lane q, defer-max THR=8 ----
      float t8[8];
#pragma unroll
      for (int r = 0; r < 8; ++r)
        t8[r] = fmaxf(fmaxf(st0[r], st0[r + 8]), fmaxf(st1[r], st1[r + 8]));
      float mt = fmaxf(fmaxf(fmaxf(t8[0], t8[1]), fmaxf(t8[2], t8[3])),
                       fmaxf(fmaxf(t8[4], t8[5]), fmaxf(t8[6], t8[7])));
      mt = fmaxf(mt, __shfl_xor(mt, 32, 64));

      if (__any(mt > m_run + 8.0f)) {
        float mn = fmaxf(m_run, mt);
        float al = fexp2(m_run - mn);
        m_run = mn;
        l_run *= al;
#pragma unroll
        for (int r = 0; r < 16; ++r) { ot0[r] *= al; ot1[r] *= al; }
      }
#pragma unroll
      for (int r = 0; r < 16; ++r) {
        st0[r] = fexp2(st0[r] - m_run);
        st1[r] = fexp2(st1[r] - m_run);
      }
      float s8[8];
#pragma unroll
      for (int r = 0; r < 8; ++r)
        s8[r] = (st0[r] + st0[r + 8]) + (st1[r] + st1[r + 8]);
      float rs = ((s8[0] + s8[1]) + (s8[2] + s8[3])) + ((s8[4] + s8[5]) + (s8[6] + s8[7]));
      rs += __shfl_xor(rs, 32, 64);
      l_run += rs;

      // ---- O^T += V^T P^T ----
      __builtin_amdgcn_s_setprio(1);
#pragma unroll
      for (int kc = 0; kc < 4; ++kc) {
        const int c = kc & 1;
        float p0, p1, p2, p3, p4, p5, p6, p7;
        if (kc < 2) {
          p0 = st0[8*c+0]; p1 = st0[8*c+1]; p2 = st0[8*c+2]; p3 = st0[8*c+3];
          p4 = st0[8*c+4]; p5 = st0[8*c+5]; p6 = st0[8*c+6]; p7 = st0[8*c+7];
        } else {
          p0 = st1[8*c+0]; p1 = st1[8*c+1]; p2 = st1[8*c+2]; p3 = st1[8*c+3];
          p4 = st1[8*c+4]; p5 = st1[8*c+5]; p6 = st1[8*c+6]; p7 = st1[8*c+7];
        }
        unsigned X0 = cvtpk(p0, p1), X1 = cvtpk(p2, p3);
        unsigned Y0 = cvtpk(p4, p5), Y1 = cvtpk(p6, p7);
        pl32swap(X0, Y0);
        pl32swap(X1, Y1);
        u32x4 u = {X0, X1, Y0, Y1};
        short8 pfk = __builtin_bit_cast(short8, u);

        const int ck = (h2 * 8) + ((kc * 2 + hi) ^ xs);   // chunk in 256B V row
        short8 v0 = *(const short8*)(vtc + lq * 256 + ck * 16);
        short8 v1 = *(const short8*)(vtc + (32 + lq) * 256 + ck * 16);
        ot0 = __builtin_amdgcn_mfma_f32_32x32x16_bf16(v0, pfk, ot0, 0, 0, 0);
        ot1 = __builtin_amdgcn_mfma_f32_32x32x16_bf16(v1, pfk, ot1, 0, 0, 0);
      }
      __builtin_amdgcn_s_setprio(0);
    }
  }

  __syncthreads();  // buffers dead; eps overlays smem

  // ---- epilogue: O^T regs -> packed u32 LDS transpose -> coalesced global ----
  // epsU[w][lq][word]: stride 33 words -> bank = (lq + word) % 32; all writes/reads
  // are b32 at <=2-way different-address aliasing (free per m136).
  unsigned (*epsU)[32][33] = (unsigned (*)[32][33])smem;
  const float rinv = 1.0f / l_run;
#pragma unroll
  for (int bq = 0; bq < 4; ++bq) {
    const int wd = bq * 4 + 2 * hi;   // e = 8*bq + 4*hi + {0,1,2,3}
    epsU[w][lq][wd]     = cvtpk(ot0[4*bq]   * rinv, ot0[4*bq+1] * rinv);
    epsU[w][lq][wd + 1] = cvtpk(ot0[4*bq+2] * rinv, ot0[4*bq+3] * rinv);
    epsU[w][lq][wd + 16]= cvtpk(ot1[4*bq]   * rinv, ot1[4*bq+1] * rinv);
    epsU[w][lq][wd + 17]= cvtpk(ot1[4*bq+2] * rinv, ot1[4*bq+3] * rinv);
  }
  asm volatile("s_waitcnt lgkmcnt(0)" ::: "memory");
  __builtin_amdgcn_sched_barrier(0);
#pragma unroll
  for (int i = 0; i < 4; ++i) {
    const int qq = i * 8 + (l >> 3), k4 = (l & 7) * 4;
    u32x4 v = {epsU[w][qq][k4], epsU[w][qq][k4 + 1],
               epsU[w][qq][k4 + 2], epsU[w][qq][k4 + 3]};
    *(short8*)(O + baseBH + (size_t)(q0 + w * 32 + qq) * 512 + (l & 7) * 8) =
        __builtin_bit_cast(short8, v);
  }
}

// ---------------- host launch ----------------

extern "C" void kernel_launch(void* const* d_in, const int* in_sizes, int n_in,
                              void* d_out, int out_size, void* d_ws, size_t ws_size,
                              hipStream_t stream) {
  const float* x1 = (const float*)d_in[0];
  const float* x2 = (const float*)d_in[1];
  const float* r  = (const float*)d_in[2];
  const float* W1 = (const float*)d_in[3];
  const float* b1 = (const float*)d_in[4];
  const float* W2 = (const float*)d_in[5];
  const float* b2 = (const float*)d_in[6];
  const float* Wq = (const float*)d_in[7];
  const float* Wk = (const float*)d_in[8];
  const float* Wv = (const float*)d_in[9];
  const float* Wo = (const float*)d_in[10];

  char* ws = (char*)d_ws;
  size_t off = 0;
  auto alloc = [&](size_t bytes) {
    char* p = ws + off;
    off = (off + bytes + 255) & ~(size_t)255;
    return p;
  };
  unsigned short* W1T = (unsigned short*)alloc(512 * 128 * 2);
  unsigned short* W2B = (unsigned short*)alloc(512 * 512 * 2);
  unsigned short* WqB = (unsigned short*)alloc(512 * 512 * 2);
  unsigned short* WkB = (unsigned short*)alloc(512 * 512 * 2);
  unsigned short* WvB = (unsigned short*)alloc(512 * 512 * 2);
  unsigned short* WoT = (unsigned short*)alloc(512 * 512 * 2);
  unsigned short* Fq  = (unsigned short*)alloc(512 * 512 * 2);
  unsigned short* Fk  = (unsigned short*)alloc(512 * 512 * 2);
  float* bqf = (float*)alloc(512 * 4);
  float* bkf = (float*)alloc(512 * 4);
  unsigned short* Xb  = (unsigned short*)alloc((size_t)32768 * 128 * 2);
  unsigned short* Hb  = (unsigned short*)alloc((size_t)32768 * 512 * 2);  // H1 | H2
  unsigned short* Rb  = (unsigned short*)alloc((size_t)16384 * 512 * 2);
  unsigned short* QHb = (unsigned short*)alloc((size_t)16384 * 512 * 2);  // reused as O
  unsigned short* KHb = (unsigned short*)alloc((size_t)16384 * 512 * 2);
  unsigned short* VT2 = (unsigned short*)alloc((size_t)512 * 16384 * 2);
  unsigned short* Ob  = QHb;

  // 1. fused weight prep (cvts + W1T + WoT + bias folds)
  prep_all<<<2560, 256, 0, stream>>>(W2, Wq, Wk, Wv, W1, Wo, b2,
                                     W2B, WqB, WkB, WvB, W1T, WoT, bqf, bkf);
  // 2. fold W2 into head projections: F[e'][c] = sum_d W*B[e'][d] * W2[c][d]
  gemm64<false, unsigned short><<<dim3(16, 1, 2), 256, 0, stream>>>(
      WqB, W2B, nullptr, Fq, 512, 4,
      WkB, W2B, nullptr, Fk, 512, 4,
      WkB, W2B, nullptr, Fk, 512, 4,
      512);
  // 3. input cvts
  cvt_all<<<12288, 256, 0, stream>>>(x1, x2, r, Xb, Rb);
  // 4. L1 for both x1,x2: Hb = relu(Xb W1 + b1), M=32768
  gemm64<true, unsigned short><<<dim3(1024, 1, 1), 256, 0, stream>>>(
      Xb, W1T, b1, Hb, 512, 4,
      Xb, W1T, b1, Hb, 512, 4,
      Xb, W1T, b1, Hb, 512, 4,
      128);
  // 5. projections: KH = H1 Fk^T + bk ; QH = H2 Fq^T + bq ; VT2 = Wv Rb^T (= VH^T)
  gemm64<false, unsigned short><<<dim3(512, 1, 3), 256, 0, stream>>>(
      Hb, Fk, bkf, KHb, 512, 4,
      Hb + (size_t)16384 * 512, Fq, bqf, QHb, 512, 4,
      WvB, Rb, nullptr, VT2, 16384, 128,
      512);
  // 6. attention (O aliases QHb: each block writes exactly the rows it read)
  attn_sw<<<dim3(64, 8), 512, 0, stream>>>(QHb, KHb, VT2, Ob);
  // 7. output projection -> f32
  gemm64<false, float><<<dim3(512, 1, 1), 256, 0, stream>>>(
      Ob, WoT, nullptr, (float*)d_out, 512, 4,
      Ob, WoT, nullptr, (float*)d_out, 512, 4,
      Ob, WoT, nullptr, (float*)d_out, 512, 4,
      512);
}

// Round 15
// 180.868 us; speedup vs baseline: 1.0644x; 1.0644x over previous
//
#include <hip/hip_runtime.h>
#include <stdint.h>

typedef __attribute__((ext_vector_type(8))) short short8;
typedef __attribute__((ext_vector_type(4))) float f32x4;
typedef __attribute__((ext_vector_type(16))) float f32x16;
typedef __attribute__((ext_vector_type(4))) unsigned u32x4;

#define DEVINL __device__ __forceinline__

DEVINL unsigned short f2bf(float f) {
  unsigned u = __float_as_uint(f);
  u = (u + 0x7FFFu + ((u >> 16) & 1u)) >> 16;
  return (unsigned short)u;
}

DEVINL void gload_lds16(const void* g, void* lds) {
  __builtin_amdgcn_global_load_lds(
      (const __attribute__((address_space(1))) unsigned int*)g,
      (__attribute__((address_space(3))) unsigned int*)lds, 16, 0, 0);
}

DEVINL float fexp2(float x) {
  float r;
  asm("v_exp_f32 %0, %1" : "=v"(r) : "v"(x));
  return r;
}

DEVINL unsigned cvtpk(float lo, float hi) {
  unsigned r;
  asm("v_cvt_pk_bf16_f32 %0, %1, %2" : "=v"(r) : "v"(lo), "v"(hi));
  return r;
}

DEVINL void pl32swap(unsigned& a, unsigned& b) {
  asm("v_permlane32_swap_b32 %0, %1" : "+v"(a), "+v"(b));
}

// ---------------- fused prep: weight cvts + W1T + WoT + bias folds + input cvts ----------------
// grid 14848 x 256.
//   bid <1024  : bf16 cvt of W2/Wq/Wk/Wv
//   bid <1280  : W1T transpose
//   bid <2304  : WoT repack
//   bid <2560  : bias folds
//   bid <14848 : x1/x2 -> Xb, r -> Rb
__global__ void prep_all(const float* __restrict__ W2, const float* __restrict__ Wq,
                         const float* __restrict__ Wk, const float* __restrict__ Wv,
                         const float* __restrict__ W1, const float* __restrict__ Wo,
                         const float* __restrict__ b2,
                         const float* __restrict__ x1, const float* __restrict__ x2,
                         const float* __restrict__ r,
                         unsigned short* __restrict__ W2B, unsigned short* __restrict__ WqB,
                         unsigned short* __restrict__ WkB, unsigned short* __restrict__ WvB,
                         unsigned short* __restrict__ W1T, unsigned short* __restrict__ WoT,
                         float* __restrict__ bqf, float* __restrict__ bkf,
                         unsigned short* __restrict__ Xb, unsigned short* __restrict__ Rb) {
  const int tid = threadIdx.x;
  int bid = blockIdx.x;
  if (bid < 1024) {
    const int a = bid >> 8;
    const int i = (bid & 255) * 256 + tid;
    const float* src = (a == 0) ? W2 : (a == 1) ? Wq : (a == 2) ? Wk : Wv;
    unsigned short* dst = (a == 0) ? W2B : (a == 1) ? WqB : (a == 2) ? WkB : WvB;
    const float scale = (a == 1) ? 0.18033688f : 1.0f;  // Wq: 1/sqrt(64) * log2(e)
    float4 v = ((const float4*)src)[i];
    ushort4 o;
    o.x = f2bf(v.x * scale); o.y = f2bf(v.y * scale);
    o.z = f2bf(v.z * scale); o.w = f2bf(v.w * scale);
    ((ushort4*)dst)[i] = o;
    return;
  }
  bid -= 1024;
  if (bid < 256) {                       // W1T[n][k] = W1[k][n], 512x128
    int idx = bid * 256 + tid;
    int n = idx >> 7, k = idx & 127;
    W1T[idx] = f2bf(W1[(size_t)k * 512 + n]);
    return;
  }
  if (bid < 1280) {                      // WoT[d][h*64+e] = Wo[h][d][e]
    int idx = (bid - 256) * 256 + tid;
    int d = idx >> 9, j = idx & 511, h = j >> 6, e = j & 63;
    WoT[idx] = f2bf(Wo[(size_t)h * 32768 + (size_t)d * 64 + e]);
    return;
  }
  if (bid < 1536) {                      // bias folds from f32 weights
    int rid = (bid - 1280) * 4 + (tid >> 6);
    int l = tid & 63;
    int e = rid & 511, which = rid >> 9;
    const float* W = which ? Wk : Wq;
    float scale = which ? 1.0f : 0.18033688f;
    float acc = 0.f;
#pragma unroll
    for (int j = 0; j < 8; ++j)
      acc += b2[l * 8 + j] * W[(size_t)e * 512 + l * 8 + j];
    acc *= scale;
#pragma unroll
    for (int off = 1; off < 64; off <<= 1) acc += __shfl_xor(acc, off, 64);
    if (l == 0) (which ? bkf : bqf)[e] = acc;
    return;
  }
  bid -= 1536;                           // input cvts, 12288 blocks
  const float* src;
  unsigned short* dst;
  int i;
  if (bid < 2048)      { src = x1; dst = Xb;           i = bid * 256 + tid; }
  else if (bid < 4096) { src = x2; dst = Xb + 2097152; i = (bid - 2048) * 256 + tid; }
  else                 { src = r;  dst = Rb;           i = (bid - 4096) * 256 + tid; }
  float4 v = ((const float4*)src)[i];
  ushort4 o;
  o.x = f2bf(v.x); o.y = f2bf(v.y); o.z = f2bf(v.z); o.w = f2bf(v.w);
  ((ushort4*)dst)[i] = o;
}

// ---------------- GEMM: C[M,N] = A[M,K]*Bt[N,K]^T, BK=64, pipelined single-buffer ----------------
// z-batched (up to 3 problems, per-z N and grid-cols nx; shared K). grid (nwg, 1, nz).
template <bool RELU, typename TOut>
__global__ __launch_bounds__(256) void gemm64(
    const unsigned short* A0, const unsigned short* B0, const float* bias0, TOut* C0, int N0, int nx0,
    const unsigned short* A1, const unsigned short* B1, const float* bias1, TOut* C1, int N1, int nx1,
    const unsigned short* A2, const unsigned short* B2, const float* bias2, TOut* C2, int N2, int nx2,
    int K) {
  __shared__ __align__(16) char smem[32768];
  unsigned short* As = (unsigned short*)smem;
  unsigned short* Bs = (unsigned short*)(smem + 16384);

  const int z = blockIdx.z;
  const unsigned short* A = (z == 0) ? A0 : (z == 1) ? A1 : A2;
  const unsigned short* Bt = (z == 0) ? B0 : (z == 1) ? B1 : B2;
  const float* bias = (z == 0) ? bias0 : (z == 1) ? bias1 : bias2;
  TOut* C = (z == 0) ? C0 : (z == 1) ? C1 : C2;
  const int N = (z == 0) ? N0 : (z == 1) ? N1 : N2;
  const int nx = (z == 0) ? nx0 : (z == 1) ? nx1 : nx2;

  // XCD-chunked block swizzle
  int id = blockIdx.x;
  const int nwg = gridDim.x;
  if ((nwg & 7) == 0) id = (id & 7) * (nwg >> 3) + (id >> 3);
  const int n0 = (id % nx) * 128, m0 = (id / nx) * 128;

  const int tid = threadIdx.x, w = tid >> 6, l = tid & 63;
  const int wm = w >> 1, wn = w & 1;
  const int lr = l & 15, lg = l >> 4;
  const int nt = K >> 6;

  f32x4 zero4 = {0.f, 0.f, 0.f, 0.f};
  f32x4 acc[4][4];
#pragma unroll
  for (int i = 0; i < 4; ++i)
#pragma unroll
    for (int j = 0; j < 4; ++j) acc[i][j] = zero4;

  auto STAGE = [&](int t) {
#pragma unroll
    for (int i = 0; i < 4; ++i) {
      const int c = i * 256 + tid;                 // 16B chunk id, 0..1023
      const int row = c >> 3, ch = c & 7;
      const int sl = (ch ^ (row & 7)) * 8;         // pre-swizzled global source
      gload_lds16(A + (size_t)(m0 + row) * K + t * 64 + sl, (char*)As + c * 16);
      gload_lds16(Bt + (size_t)(n0 + row) * K + t * 64 + sl, (char*)Bs + c * 16);
    }
  };

  STAGE(0);
  for (int t = 0; t < nt; ++t) {
    asm volatile("s_waitcnt vmcnt(0)" ::: "memory");   // tile t landed
    __builtin_amdgcn_s_barrier();
    // ---- drain LDS into register frags (frees the buffer) ----
    short8 af[2][4], bfr[2][4];
#pragma unroll
    for (int kk = 0; kk < 2; ++kk) {
#pragma unroll
      for (int mi = 0; mi < 4; ++mi) {
        const int row = wm * 64 + mi * 16 + lr;
        af[kk][mi] = *(const short8*)((const char*)As + row * 128 + (((kk * 4 + lg) ^ (row & 7)) * 16));
      }
#pragma unroll
      for (int ni = 0; ni < 4; ++ni) {
        const int row = wn * 64 + ni * 16 + lr;
        bfr[kk][ni] = *(const short8*)((const char*)Bs + row * 128 + (((kk * 4 + lg) ^ (row & 7)) * 16));
      }
    }
    asm volatile("s_waitcnt lgkmcnt(0)" ::: "memory");
    __builtin_amdgcn_s_barrier();                      // all waves done reading LDS
    if (t + 1 < nt) STAGE(t + 1);                      // overwrite under the MFMAs
    __builtin_amdgcn_sched_barrier(0);
#pragma unroll
    for (int kk = 0; kk < 2; ++kk)
#pragma unroll
      for (int mi = 0; mi < 4; ++mi)
#pragma unroll
        for (int ni = 0; ni < 4; ++ni)
          acc[mi][ni] = __builtin_amdgcn_mfma_f32_16x16x32_bf16(af[kk][mi], bfr[kk][ni], acc[mi][ni], 0, 0, 0);
  }

#pragma unroll
  for (int ni = 0; ni < 4; ++ni) {
    const int col = n0 + wn * 64 + ni * 16 + lr;
    const float bv = bias ? bias[col] : 0.f;
#pragma unroll
    for (int mi = 0; mi < 4; ++mi) {
      const int row = m0 + wm * 64 + mi * 16 + lg * 4;
#pragma unroll
      for (int r = 0; r < 4; ++r) {
        float v = acc[mi][ni][r] + bv;
        if (RELU) v = fmaxf(v, 0.f);
        if constexpr (sizeof(TOut) == 2)
          C[(size_t)(row + r) * N + col] = (TOut)f2bf(v);
        else
          C[(size_t)(row + r) * N + col] = v;
      }
    }
  }
}

// ---------------- flash attention: ring-3 counted-vmcnt, swapped 32x32, defer-max ----------------
// VT2: [512 e_g][16384 n_g] bf16 (e_g = h*64+e, n_g = b*2048+n)
DEVINL void stage_kv(const unsigned short* Kp, const unsigned short* Vp,
                     char* kb, char* vb, int tid, int k0) {
  const int row = tid >> 3, cs = tid & 7;
  const int sl = (cs ^ (row & 7)) * 8;
  gload_lds16(Kp + (size_t)(k0 + row) * 512 + sl, kb + tid * 16);
  gload_lds16(Vp + (size_t)row * 16384 + k0 + sl, vb + tid * 16);
}

__global__ __launch_bounds__(512) void attn_sw(
    const unsigned short* __restrict__ Q, const unsigned short* __restrict__ Kh,
    const unsigned short* __restrict__ VT2, unsigned short* __restrict__ O) {
  const int bh = blockIdx.x, b = bh >> 3, h = bh & 7;
  const int q0 = blockIdx.y * 256;
  const int tid = threadIdx.x, w = tid >> 6, l = tid & 63;
  const int lq = l & 31, hi = l >> 5;
  const size_t baseBH = (size_t)b * 2048 * 512 + (size_t)h * 64;

  __shared__ __align__(16) char smem[49152];  // K ring 3x8K | V ring 3x8K; eps overlays
  char* vb0 = smem + 24576;

  const unsigned short* Kp = Kh + baseBH;
  const unsigned short* Vp = VT2 + (size_t)(h * 64) * 16384 + (size_t)b * 2048;

  // ---- Q direct to registers ----
  short8 qf[4];
  {
    const unsigned short* qp = Q + baseBH + (size_t)(q0 + w * 32 + lq) * 512 + hi * 8;
#pragma unroll
    for (int kc = 0; kc < 4; ++kc) qf[kc] = *(const short8*)(qp + kc * 16);
  }

  f32x16 ot0 = {0,0,0,0,0,0,0,0,0,0,0,0,0,0,0,0};
  f32x16 ot1 = {0,0,0,0,0,0,0,0,0,0,0,0,0,0,0,0};
  float m_run = -1e30f, l_run = 0.f;
  const int xs = (lq & 7);

  stage_kv(Kp, Vp, smem, vb0, tid, 0);
  stage_kv(Kp, Vp, smem + 8192, vb0 + 8192, tid, 64);

  for (int t = 0; t < 32; ++t) {
    if (t < 31) asm volatile("s_waitcnt vmcnt(2)" ::: "memory");
    else        asm volatile("s_waitcnt vmcnt(0)" ::: "memory");
    __builtin_amdgcn_s_barrier();   // raw: keeps prefetch loads in flight
    if (t < 30) {
      const int tn = t + 2, rb = tn - (tn / 3) * 3;
      stage_kv(Kp, Vp, smem + rb * 8192, vb0 + rb * 8192, tid, tn * 64);
    }
    const int cb = t - (t / 3) * 3;
    const char* klc = smem + cb * 8192;
    const char* vtc = vb0 + cb * 8192;

    // ---- S^T = K Q^T ----
    f32x16 st0 = {0,0,0,0,0,0,0,0,0,0,0,0,0,0,0,0};
    f32x16 st1 = {0,0,0,0,0,0,0,0,0,0,0,0,0,0,0,0};
    __builtin_amdgcn_s_setprio(1);
#pragma unroll
    for (int kc = 0; kc < 4; ++kc) {
      const int sl = ((kc * 2 + hi) ^ xs) * 16;
      short8 kf0 = *(const short8*)(klc + lq * 128 + sl);
      short8 kf1 = *(const short8*)(klc + (32 + lq) * 128 + sl);
      st0 = __builtin_amdgcn_mfma_f32_32x32x16_bf16(kf0, qf[kc], st0, 0, 0, 0);
      st1 = __builtin_amdgcn_mfma_f32_32x32x16_bf16(kf1, qf[kc], st1, 0, 0, 0);
    }
    __builtin_amdgcn_s_setprio(0);

    // ---- online softmax (log2 domain), per-lane q, defer-max THR=8 ----
    float t8[8];
#pragma unroll
    for (int r = 0; r < 8; ++r)
      t8[r] = fmaxf(fmaxf(st0[r], st0[r + 8]), fmaxf(st1[r], st1[r + 8]));
    float mt = fmaxf(fmaxf(fmaxf(t8[0], t8[1]), fmaxf(t8[2], t8[3])),
                     fmaxf(fmaxf(t8[4], t8[5]), fmaxf(t8[6], t8[7])));
    mt = fmaxf(mt, __shfl_xor(mt, 32, 64));

    if (__any(mt > m_run + 8.0f)) {
      float mn = fmaxf(m_run, mt);
      float al = fexp2(m_run - mn);
      m_run = mn;
      l_run *= al;
#pragma unroll
      for (int r = 0; r < 16; ++r) { ot0[r] *= al; ot1[r] *= al; }
    }
#pragma unroll
    for (int r = 0; r < 16; ++r) {
      st0[r] = fexp2(st0[r] - m_run);
      st1[r] = fexp2(st1[r] - m_run);
    }
    float s8[8];
#pragma unroll
    for (int r = 0; r < 8; ++r)
      s8[r] = (st0[r] + st0[r + 8]) + (st1[r] + st1[r + 8]);
    float rs = ((s8[0] + s8[1]) + (s8[2] + s8[3])) + ((s8[4] + s8[5]) + (s8[6] + s8[7]));
    rs += __shfl_xor(rs, 32, 64);
    l_run += rs;

    // ---- O^T += V^T P^T ----
    __builtin_amdgcn_s_setprio(1);
#pragma unroll
    for (int kc = 0; kc < 4; ++kc) {
      const int c = kc & 1;
      float p0, p1, p2, p3, p4, p5, p6, p7;
      if (kc < 2) {
        p0 = st0[8*c+0]; p1 = st0[8*c+1]; p2 = st0[8*c+2]; p3 = st0[8*c+3];
        p4 = st0[8*c+4]; p5 = st0[8*c+5]; p6 = st0[8*c+6]; p7 = st0[8*c+7];
      } else {
        p0 = st1[8*c+0]; p1 = st1[8*c+1]; p2 = st1[8*c+2]; p3 = st1[8*c+3];
        p4 = st1[8*c+4]; p5 = st1[8*c+5]; p6 = st1[8*c+6]; p7 = st1[8*c+7];
      }
      unsigned X0 = cvtpk(p0, p1), X1 = cvtpk(p2, p3);
      unsigned Y0 = cvtpk(p4, p5), Y1 = cvtpk(p6, p7);
      pl32swap(X0, Y0);
      pl32swap(X1, Y1);
      u32x4 u = {X0, X1, Y0, Y1};
      short8 pfk = __builtin_bit_cast(short8, u);

      const int sl = ((kc * 2 + hi) ^ xs) * 16;
      short8 v0 = *(const short8*)(vtc + lq * 128 + sl);
      short8 v1 = *(const short8*)(vtc + (32 + lq) * 128 + sl);
      ot0 = __builtin_amdgcn_mfma_f32_32x32x16_bf16(v0, pfk, ot0, 0, 0, 0);
      ot1 = __builtin_amdgcn_mfma_f32_32x32x16_bf16(v1, pfk, ot1, 0, 0, 0);
    }
    __builtin_amdgcn_s_setprio(0);
  }

  __syncthreads();  // ring buffers dead; eps overlays smem

  // ---- epilogue: O^T regs -> LDS transpose -> coalesced global ----
  unsigned short (*eps)[32][66] = (unsigned short (*)[32][66])smem;
  const float rinv = 1.0f / l_run;
#pragma unroll
  for (int r = 0; r < 16; ++r) {
    const int e = (r & 3) + 8 * (r >> 2) + 4 * hi;
    eps[w][lq][e] = f2bf(ot0[r] * rinv);
    eps[w][lq][e + 32] = f2bf(ot1[r] * rinv);
  }
  asm volatile("s_waitcnt lgkmcnt(0)" ::: "memory");
  __builtin_amdgcn_sched_barrier(0);
#pragma unroll
  for (int i = 0; i < 4; ++i) {
    const int qq = i * 8 + (l >> 3), e0 = (l & 7) * 8;
    short8 v = *(const short8*)&eps[w][qq][e0];
    *(short8*)(O + baseBH + (size_t)(q0 + w * 32 + qq) * 512 + e0) = v;
  }
}

// ---------------- host launch ----------------

extern "C" void kernel_launch(void* const* d_in, const int* in_sizes, int n_in,
                              void* d_out, int out_size, void* d_ws, size_t ws_size,
                              hipStream_t stream) {
  const float* x1 = (const float*)d_in[0];
  const float* x2 = (const float*)d_in[1];
  const float* r  = (const float*)d_in[2];
  const float* W1 = (const float*)d_in[3];
  const float* b1 = (const float*)d_in[4];
  const float* W2 = (const float*)d_in[5];
  const float* b2 = (const float*)d_in[6];
  const float* Wq = (const float*)d_in[7];
  const float* Wk = (const float*)d_in[8];
  const float* Wv = (const float*)d_in[9];
  const float* Wo = (const float*)d_in[10];

  char* ws = (char*)d_ws;
  size_t off = 0;
  auto alloc = [&](size_t bytes) {
    char* p = ws + off;
    off = (off + bytes + 255) & ~(size_t)255;
    return p;
  };
  unsigned short* W1T = (unsigned short*)alloc(512 * 128 * 2);
  unsigned short* W2B = (unsigned short*)alloc(512 * 512 * 2);
  unsigned short* WqB = (unsigned short*)alloc(512 * 512 * 2);
  unsigned short* WkB = (unsigned short*)alloc(512 * 512 * 2);
  unsigned short* WvB = (unsigned short*)alloc(512 * 512 * 2);
  unsigned short* WoT = (unsigned short*)alloc(512 * 512 * 2);
  unsigned short* Fq  = (unsigned short*)alloc(512 * 512 * 2);
  unsigned short* Fk  = (unsigned short*)alloc(512 * 512 * 2);
  float* bqf = (float*)alloc(512 * 4);
  float* bkf = (float*)alloc(512 * 4);
  unsigned short* Xb  = (unsigned short*)alloc((size_t)32768 * 128 * 2);
  unsigned short* Hb  = (unsigned short*)alloc((size_t)32768 * 512 * 2);  // H1 | H2
  unsigned short* Rb  = (unsigned short*)alloc((size_t)16384 * 512 * 2);
  unsigned short* QHb = (unsigned short*)alloc((size_t)16384 * 512 * 2);  // reused as O
  unsigned short* KHb = (unsigned short*)alloc((size_t)16384 * 512 * 2);
  unsigned short* VT2 = (unsigned short*)alloc((size_t)512 * 16384 * 2);
  unsigned short* Ob  = QHb;

  // 1. fused prep (weight cvts + W1T + WoT + bias folds + input cvts)
  prep_all<<<14848, 256, 0, stream>>>(W2, Wq, Wk, Wv, W1, Wo, b2, x1, x2, r,
                                      W2B, WqB, WkB, WvB, W1T, WoT, bqf, bkf,
                                      Xb, Rb);
  // 2. fold W2 into head projections: F[e'][c] = sum_d W*B[e'][d] * W2[c][d]
  gemm64<false, unsigned short><<<dim3(16, 1, 2), 256, 0, stream>>>(
      WqB, W2B, nullptr, Fq, 512, 4,
      WkB, W2B, nullptr, Fk, 512, 4,
      WkB, W2B, nullptr, Fk, 512, 4,
      512);
  // 3. L1 for both x1,x2: Hb = relu(Xb W1 + b1), M=32768
  gemm64<true, unsigned short><<<dim3(1024, 1, 1), 256, 0, stream>>>(
      Xb, W1T, b1, Hb, 512, 4,
      Xb, W1T, b1, Hb, 512, 4,
      Xb, W1T, b1, Hb, 512, 4,
      128);
  // 4. projections: KH = H1 Fk^T + bk ; QH = H2 Fq^T + bq ; VT2 = Wv Rb^T (= VH^T)
  gemm64<false, unsigned short><<<dim3(512, 1, 3), 256, 0, stream>>>(
      Hb, Fk, bkf, KHb, 512, 4,
      Hb + (size_t)16384 * 512, Fq, bqf, QHb, 512, 4,
      WvB, Rb, nullptr, VT2, 16384, 128,
      512);
  // 5. attention (O aliases QHb: each block writes exactly the rows it read)
  attn_sw<<<dim3(64, 8), 512, 0, stream>>>(QHb, KHb, VT2, Ob);
  // 6. output projection -> f32
  gemm64<false, float><<<dim3(512, 1, 1), 256, 0, stream>>>(
      Ob, WoT, nullptr, (float*)d_out, 512, 4,
      Ob, WoT, nullptr, (float*)d_out, 512, 4,
      Ob, WoT, nullptr, (float*)d_out, 512, 4,
      512);
}

// Round 16
// 175.641 us; speedup vs baseline: 1.0961x; 1.0298x over previous
//
#include <hip/hip_runtime.h>
#include <stdint.h>

typedef __attribute__((ext_vector_type(8))) short short8;
typedef __attribute__((ext_vector_type(4))) float f32x4;
typedef __attribute__((ext_vector_type(16))) float f32x16;
typedef __attribute__((ext_vector_type(4))) unsigned u32x4;

#define DEVINL __device__ __forceinline__

DEVINL unsigned short f2bf(float f) {
  unsigned u = __float_as_uint(f);
  u = (u + 0x7FFFu + ((u >> 16) & 1u)) >> 16;
  return (unsigned short)u;
}

DEVINL void gload_lds16(const void* g, void* lds) {
  __builtin_amdgcn_global_load_lds(
      (const __attribute__((address_space(1))) unsigned int*)g,
      (__attribute__((address_space(3))) unsigned int*)lds, 16, 0, 0);
}

DEVINL float fexp2(float x) {
  float r;
  asm("v_exp_f32 %0, %1" : "=v"(r) : "v"(x));
  return r;
}

DEVINL unsigned cvtpk(float lo, float hi) {
  unsigned r;
  asm("v_cvt_pk_bf16_f32 %0, %1, %2" : "=v"(r) : "v"(lo), "v"(hi));
  return r;
}

DEVINL void pl32swap(unsigned& a, unsigned& b) {
  asm("v_permlane32_swap_b32 %0, %1" : "+v"(a), "+v"(b));
}

// ---------------- fused prep: weight cvts + W1T + WoT + bias folds + input cvts ----------------
// grid 14848 x 256.
__global__ void prep_all(const float* __restrict__ W2, const float* __restrict__ Wq,
                         const float* __restrict__ Wk, const float* __restrict__ Wv,
                         const float* __restrict__ W1, const float* __restrict__ Wo,
                         const float* __restrict__ b2,
                         const float* __restrict__ x1, const float* __restrict__ x2,
                         const float* __restrict__ r,
                         unsigned short* __restrict__ W2B, unsigned short* __restrict__ WqB,
                         unsigned short* __restrict__ WkB, unsigned short* __restrict__ WvB,
                         unsigned short* __restrict__ W1T, unsigned short* __restrict__ WoT,
                         float* __restrict__ bqf, float* __restrict__ bkf,
                         unsigned short* __restrict__ Xb, unsigned short* __restrict__ Rb) {
  const int tid = threadIdx.x;
  int bid = blockIdx.x;
  if (bid < 1024) {
    const int a = bid >> 8;
    const int i = (bid & 255) * 256 + tid;
    const float* src = (a == 0) ? W2 : (a == 1) ? Wq : (a == 2) ? Wk : Wv;
    unsigned short* dst = (a == 0) ? W2B : (a == 1) ? WqB : (a == 2) ? WkB : WvB;
    const float scale = (a == 1) ? 0.18033688f : 1.0f;  // Wq: 1/sqrt(64) * log2(e)
    float4 v = ((const float4*)src)[i];
    ushort4 o;
    o.x = f2bf(v.x * scale); o.y = f2bf(v.y * scale);
    o.z = f2bf(v.z * scale); o.w = f2bf(v.w * scale);
    ((ushort4*)dst)[i] = o;
    return;
  }
  bid -= 1024;
  if (bid < 256) {                       // W1T[n][k] = W1[k][n], 512x128
    int idx = bid * 256 + tid;
    int n = idx >> 7, k = idx & 127;
    W1T[idx] = f2bf(W1[(size_t)k * 512 + n]);
    return;
  }
  if (bid < 1280) {                      // WoT[d][h*64+e] = Wo[h][d][e]
    int idx = (bid - 256) * 256 + tid;
    int d = idx >> 9, j = idx & 511, h = j >> 6, e = j & 63;
    WoT[idx] = f2bf(Wo[(size_t)h * 32768 + (size_t)d * 64 + e]);
    return;
  }
  if (bid < 1536) {                      // bias folds from f32 weights
    int rid = (bid - 1280) * 4 + (tid >> 6);
    int l = tid & 63;
    int e = rid & 511, which = rid >> 9;
    const float* W = which ? Wk : Wq;
    float scale = which ? 1.0f : 0.18033688f;
    float acc = 0.f;
#pragma unroll
    for (int j = 0; j < 8; ++j)
      acc += b2[l * 8 + j] * W[(size_t)e * 512 + l * 8 + j];
    acc *= scale;
#pragma unroll
    for (int off = 1; off < 64; off <<= 1) acc += __shfl_xor(acc, off, 64);
    if (l == 0) (which ? bkf : bqf)[e] = acc;
    return;
  }
  bid -= 1536;                           // input cvts, 12288 blocks
  const float* src;
  unsigned short* dst;
  int i;
  if (bid < 2048)      { src = x1; dst = Xb;           i = bid * 256 + tid; }
  else if (bid < 4096) { src = x2; dst = Xb + 2097152; i = (bid - 2048) * 256 + tid; }
  else                 { src = r;  dst = Rb;           i = (bid - 4096) * 256 + tid; }
  float4 v = ((const float4*)src)[i];
  ushort4 o;
  o.x = f2bf(v.x); o.y = f2bf(v.y); o.z = f2bf(v.z); o.w = f2bf(v.w);
  ((ushort4*)dst)[i] = o;
}

// ---------------- GEMM: C[M,N] = A[M,K]*Bt[N,K]^T, BK=64, pipelined single-buffer ----------------
// z-batched (up to 3 problems; per-z N, grid-cols nx, K, block-count nwg, relu).
// grid (max_nwg, 1, nz); blocks with blockIdx.x >= nwg[z] exit early.
template <typename TOut>
__global__ __launch_bounds__(256) void gemm64(
    const unsigned short* A0, const unsigned short* B0, const float* bias0, TOut* C0,
    int N0, int nx0, int K0, int nwg0, int relu0,
    const unsigned short* A1, const unsigned short* B1, const float* bias1, TOut* C1,
    int N1, int nx1, int K1, int nwg1, int relu1,
    const unsigned short* A2, const unsigned short* B2, const float* bias2, TOut* C2,
    int N2, int nx2, int K2, int nwg2, int relu2) {
  __shared__ __align__(16) char smem[32768];
  unsigned short* As = (unsigned short*)smem;
  unsigned short* Bs = (unsigned short*)(smem + 16384);

  const int z = blockIdx.z;
  const unsigned short* A = (z == 0) ? A0 : (z == 1) ? A1 : A2;
  const unsigned short* Bt = (z == 0) ? B0 : (z == 1) ? B1 : B2;
  const float* bias = (z == 0) ? bias0 : (z == 1) ? bias1 : bias2;
  TOut* C = (z == 0) ? C0 : (z == 1) ? C1 : C2;
  const int N = (z == 0) ? N0 : (z == 1) ? N1 : N2;
  const int nx = (z == 0) ? nx0 : (z == 1) ? nx1 : nx2;
  const int K = (z == 0) ? K0 : (z == 1) ? K1 : K2;
  const int nwg = (z == 0) ? nwg0 : (z == 1) ? nwg1 : nwg2;
  const int relu = (z == 0) ? relu0 : (z == 1) ? relu1 : relu2;

  if (blockIdx.x >= nwg) return;

  // XCD-chunked block swizzle over this problem's nwg
  int id = blockIdx.x;
  if ((nwg & 7) == 0) id = (id & 7) * (nwg >> 3) + (id >> 3);
  const int n0 = (id % nx) * 128, m0 = (id / nx) * 128;

  const int tid = threadIdx.x, w = tid >> 6, l = tid & 63;
  const int wm = w >> 1, wn = w & 1;
  const int lr = l & 15, lg = l >> 4;
  const int nt = K >> 6;

  f32x4 zero4 = {0.f, 0.f, 0.f, 0.f};
  f32x4 acc[4][4];
#pragma unroll
  for (int i = 0; i < 4; ++i)
#pragma unroll
    for (int j = 0; j < 4; ++j) acc[i][j] = zero4;

  auto STAGE = [&](int t) {
#pragma unroll
    for (int i = 0; i < 4; ++i) {
      const int c = i * 256 + tid;                 // 16B chunk id, 0..1023
      const int row = c >> 3, ch = c & 7;
      const int sl = (ch ^ (row & 7)) * 8;         // pre-swizzled global source
      gload_lds16(A + (size_t)(m0 + row) * K + t * 64 + sl, (char*)As + c * 16);
      gload_lds16(Bt + (size_t)(n0 + row) * K + t * 64 + sl, (char*)Bs + c * 16);
    }
  };

  STAGE(0);
  for (int t = 0; t < nt; ++t) {
    asm volatile("s_waitcnt vmcnt(0)" ::: "memory");   // tile t landed
    __builtin_amdgcn_s_barrier();
    // ---- drain LDS into register frags (frees the buffer) ----
    short8 af[2][4], bfr[2][4];
#pragma unroll
    for (int kk = 0; kk < 2; ++kk) {
#pragma unroll
      for (int mi = 0; mi < 4; ++mi) {
        const int row = wm * 64 + mi * 16 + lr;
        af[kk][mi] = *(const short8*)((const char*)As + row * 128 + (((kk * 4 + lg) ^ (row & 7)) * 16));
      }
#pragma unroll
      for (int ni = 0; ni < 4; ++ni) {
        const int row = wn * 64 + ni * 16 + lr;
        bfr[kk][ni] = *(const short8*)((const char*)Bs + row * 128 + (((kk * 4 + lg) ^ (row & 7)) * 16));
      }
    }
    asm volatile("s_waitcnt lgkmcnt(0)" ::: "memory");
    __builtin_amdgcn_s_barrier();                      // all waves done reading LDS
    if (t + 1 < nt) STAGE(t + 1);                      // overwrite under the MFMAs
    __builtin_amdgcn_sched_barrier(0);
#pragma unroll
    for (int kk = 0; kk < 2; ++kk)
#pragma unroll
      for (int mi = 0; mi < 4; ++mi)
#pragma unroll
        for (int ni = 0; ni < 4; ++ni)
          acc[mi][ni] = __builtin_amdgcn_mfma_f32_16x16x32_bf16(af[kk][mi], bfr[kk][ni], acc[mi][ni], 0, 0, 0);
  }

#pragma unroll
  for (int ni = 0; ni < 4; ++ni) {
    const int col = n0 + wn * 64 + ni * 16 + lr;
    const float bv = bias ? bias[col] : 0.f;
#pragma unroll
    for (int mi = 0; mi < 4; ++mi) {
      const int row = m0 + wm * 64 + mi * 16 + lg * 4;
#pragma unroll
      for (int r = 0; r < 4; ++r) {
        float v = acc[mi][ni][r] + bv;
        if (relu) v = fmaxf(v, 0.f);
        if constexpr (sizeof(TOut) == 2)
          C[(size_t)(row + r) * N + col] = (TOut)f2bf(v);
        else
          C[(size_t)(row + r) * N + col] = v;
      }
    }
  }
}

// ---------------- flash attention: ring-3 counted-vmcnt, swapped 32x32, defer-max ----------------
// VT2: [512 e_g][16384 n_g] bf16 (e_g = h*64+e, n_g = b*2048+n)
DEVINL void stage_kv(const unsigned short* Kp, const unsigned short* Vp,
                     char* kb, char* vb, int tid, int k0) {
  const int row = tid >> 3, cs = tid & 7;
  const int sl = (cs ^ (row & 7)) * 8;
  gload_lds16(Kp + (size_t)(k0 + row) * 512 + sl, kb + tid * 16);
  gload_lds16(Vp + (size_t)row * 16384 + k0 + sl, vb + tid * 16);
}

__global__ __launch_bounds__(512) void attn_sw(
    const unsigned short* __restrict__ Q, const unsigned short* __restrict__ Kh,
    const unsigned short* __restrict__ VT2, unsigned short* __restrict__ O) {
  const int bh = blockIdx.x, b = bh >> 3, h = bh & 7;
  const int q0 = blockIdx.y * 256;
  const int tid = threadIdx.x, w = tid >> 6, l = tid & 63;
  const int lq = l & 31, hi = l >> 5;
  const size_t baseBH = (size_t)b * 2048 * 512 + (size_t)h * 64;

  __shared__ __align__(16) char smem[49152];  // K ring 3x8K | V ring 3x8K; eps overlays
  char* vb0 = smem + 24576;

  const unsigned short* Kp = Kh + baseBH;
  const unsigned short* Vp = VT2 + (size_t)(h * 64) * 16384 + (size_t)b * 2048;

  // ---- Q direct to registers ----
  short8 qf[4];
  {
    const unsigned short* qp = Q + baseBH + (size_t)(q0 + w * 32 + lq) * 512 + hi * 8;
#pragma unroll
    for (int kc = 0; kc < 4; ++kc) qf[kc] = *(const short8*)(qp + kc * 16);
  }

  f32x16 ot0 = {0,0,0,0,0,0,0,0,0,0,0,0,0,0,0,0};
  f32x16 ot1 = {0,0,0,0,0,0,0,0,0,0,0,0,0,0,0,0};
  float m_run = -1e30f, l_run = 0.f;
  const int xs = (lq & 7);

  stage_kv(Kp, Vp, smem, vb0, tid, 0);
  stage_kv(Kp, Vp, smem + 8192, vb0 + 8192, tid, 64);

  for (int t = 0; t < 32; ++t) {
    if (t < 31) asm volatile("s_waitcnt vmcnt(2)" ::: "memory");
    else        asm volatile("s_waitcnt vmcnt(0)" ::: "memory");
    __builtin_amdgcn_s_barrier();   // raw: keeps prefetch loads in flight
    if (t < 30) {
      const int tn = t + 2, rb = tn - (tn / 3) * 3;
      stage_kv(Kp, Vp, smem + rb * 8192, vb0 + rb * 8192, tid, tn * 64);
    }
    const int cb = t - (t / 3) * 3;
    const char* klc = smem + cb * 8192;
    const char* vtc = vb0 + cb * 8192;

    // ---- S^T = K Q^T ----
    f32x16 st0 = {0,0,0,0,0,0,0,0,0,0,0,0,0,0,0,0};
    f32x16 st1 = {0,0,0,0,0,0,0,0,0,0,0,0,0,0,0,0};
    __builtin_amdgcn_s_setprio(1);
#pragma unroll
    for (int kc = 0; kc < 4; ++kc) {
      const int sl = ((kc * 2 + hi) ^ xs) * 16;
      short8 kf0 = *(const short8*)(klc + lq * 128 + sl);
      short8 kf1 = *(const short8*)(klc + (32 + lq) * 128 + sl);
      st0 = __builtin_amdgcn_mfma_f32_32x32x16_bf16(kf0, qf[kc], st0, 0, 0, 0);
      st1 = __builtin_amdgcn_mfma_f32_32x32x16_bf16(kf1, qf[kc], st1, 0, 0, 0);
    }
    __builtin_amdgcn_s_setprio(0);

    // ---- online softmax (log2 domain), per-lane q, defer-max THR=8 ----
    float t8[8];
#pragma unroll
    for (int r = 0; r < 8; ++r)
      t8[r] = fmaxf(fmaxf(st0[r], st0[r + 8]), fmaxf(st1[r], st1[r + 8]));
    float mt = fmaxf(fmaxf(fmaxf(t8[0], t8[1]), fmaxf(t8[2], t8[3])),
                     fmaxf(fmaxf(t8[4], t8[5]), fmaxf(t8[6], t8[7])));
    mt = fmaxf(mt, __shfl_xor(mt, 32, 64));

    if (__any(mt > m_run + 8.0f)) {
      float mn = fmaxf(m_run, mt);
      float al = fexp2(m_run - mn);
      m_run = mn;
      l_run *= al;
#pragma unroll
      for (int r = 0; r < 16; ++r) { ot0[r] *= al; ot1[r] *= al; }
    }
#pragma unroll
    for (int r = 0; r < 16; ++r) {
      st0[r] = fexp2(st0[r] - m_run);
      st1[r] = fexp2(st1[r] - m_run);
    }
    float s8[8];
#pragma unroll
    for (int r = 0; r < 8; ++r)
      s8[r] = (st0[r] + st0[r + 8]) + (st1[r] + st1[r + 8]);
    float rs = ((s8[0] + s8[1]) + (s8[2] + s8[3])) + ((s8[4] + s8[5]) + (s8[6] + s8[7]));
    rs += __shfl_xor(rs, 32, 64);
    l_run += rs;

    // ---- O^T += V^T P^T ----
    __builtin_amdgcn_s_setprio(1);
#pragma unroll
    for (int kc = 0; kc < 4; ++kc) {
      const int c = kc & 1;
      float p0, p1, p2, p3, p4, p5, p6, p7;
      if (kc < 2) {
        p0 = st0[8*c+0]; p1 = st0[8*c+1]; p2 = st0[8*c+2]; p3 = st0[8*c+3];
        p4 = st0[8*c+4]; p5 = st0[8*c+5]; p6 = st0[8*c+6]; p7 = st0[8*c+7];
      } else {
        p0 = st1[8*c+0]; p1 = st1[8*c+1]; p2 = st1[8*c+2]; p3 = st1[8*c+3];
        p4 = st1[8*c+4]; p5 = st1[8*c+5]; p6 = st1[8*c+6]; p7 = st1[8*c+7];
      }
      unsigned X0 = cvtpk(p0, p1), X1 = cvtpk(p2, p3);
      unsigned Y0 = cvtpk(p4, p5), Y1 = cvtpk(p6, p7);
      pl32swap(X0, Y0);
      pl32swap(X1, Y1);
      u32x4 u = {X0, X1, Y0, Y1};
      short8 pfk = __builtin_bit_cast(short8, u);

      const int sl = ((kc * 2 + hi) ^ xs) * 16;
      short8 v0 = *(const short8*)(vtc + lq * 128 + sl);
      short8 v1 = *(const short8*)(vtc + (32 + lq) * 128 + sl);
      ot0 = __builtin_amdgcn_mfma_f32_32x32x16_bf16(v0, pfk, ot0, 0, 0, 0);
      ot1 = __builtin_amdgcn_mfma_f32_32x32x16_bf16(v1, pfk, ot1, 0, 0, 0);
    }
    __builtin_amdgcn_s_setprio(0);
  }

  __syncthreads();  // ring buffers dead; eps overlays smem

  // ---- epilogue: O^T regs -> LDS transpose -> coalesced global ----
  unsigned short (*eps)[32][66] = (unsigned short (*)[32][66])smem;
  const float rinv = 1.0f / l_run;
#pragma unroll
  for (int r = 0; r < 16; ++r) {
    const int e = (r & 3) + 8 * (r >> 2) + 4 * hi;
    eps[w][lq][e] = f2bf(ot0[r] * rinv);
    eps[w][lq][e + 32] = f2bf(ot1[r] * rinv);
  }
  asm volatile("s_waitcnt lgkmcnt(0)" ::: "memory");
  __builtin_amdgcn_sched_barrier(0);
#pragma unroll
  for (int i = 0; i < 4; ++i) {
    const int qq = i * 8 + (l >> 3), e0 = (l & 7) * 8;
    short8 v = *(const short8*)&eps[w][qq][e0];
    *(short8*)(O + baseBH + (size_t)(q0 + w * 32 + qq) * 512 + e0) = v;
  }
}

// ---------------- host launch ----------------

extern "C" void kernel_launch(void* const* d_in, const int* in_sizes, int n_in,
                              void* d_out, int out_size, void* d_ws, size_t ws_size,
                              hipStream_t stream) {
  const float* x1 = (const float*)d_in[0];
  const float* x2 = (const float*)d_in[1];
  const float* r  = (const float*)d_in[2];
  const float* W1 = (const float*)d_in[3];
  const float* b1 = (const float*)d_in[4];
  const float* W2 = (const float*)d_in[5];
  const float* b2 = (const float*)d_in[6];
  const float* Wq = (const float*)d_in[7];
  const float* Wk = (const float*)d_in[8];
  const float* Wv = (const float*)d_in[9];
  const float* Wo = (const float*)d_in[10];

  char* ws = (char*)d_ws;
  size_t off = 0;
  auto alloc = [&](size_t bytes) {
    char* p = ws + off;
    off = (off + bytes + 255) & ~(size_t)255;
    return p;
  };
  unsigned short* W1T = (unsigned short*)alloc(512 * 128 * 2);
  unsigned short* W2B = (unsigned short*)alloc(512 * 512 * 2);
  unsigned short* WqB = (unsigned short*)alloc(512 * 512 * 2);
  unsigned short* WkB = (unsigned short*)alloc(512 * 512 * 2);
  unsigned short* WvB = (unsigned short*)alloc(512 * 512 * 2);
  unsigned short* WoT = (unsigned short*)alloc(512 * 512 * 2);
  unsigned short* Fq  = (unsigned short*)alloc(512 * 512 * 2);
  unsigned short* Fk  = (unsigned short*)alloc(512 * 512 * 2);
  float* bqf = (float*)alloc(512 * 4);
  float* bkf = (float*)alloc(512 * 4);
  unsigned short* Xb  = (unsigned short*)alloc((size_t)32768 * 128 * 2);
  unsigned short* Hb  = (unsigned short*)alloc((size_t)32768 * 512 * 2);  // H1 | H2
  unsigned short* Rb  = (unsigned short*)alloc((size_t)16384 * 512 * 2);
  unsigned short* QHb = (unsigned short*)alloc((size_t)16384 * 512 * 2);  // reused as O
  unsigned short* KHb = (unsigned short*)alloc((size_t)16384 * 512 * 2);
  unsigned short* VT2 = (unsigned short*)alloc((size_t)512 * 16384 * 2);
  unsigned short* Ob  = QHb;

  // 1. fused prep (weight cvts + W1T + WoT + bias folds + input cvts)
  prep_all<<<14848, 256, 0, stream>>>(W2, Wq, Wk, Wv, W1, Wo, b2, x1, x2, r,
                                      W2B, WqB, WkB, WvB, W1T, WoT, bqf, bkf,
                                      Xb, Rb);
  // 2. merged: L1 (z0, M=32768, K=128, relu) + W2-folds (z1/z2, 512^3, 16 blocks each)
  gemm64<unsigned short><<<dim3(1024, 1, 3), 256, 0, stream>>>(
      Xb,  W1T, b1,      Hb, 512, 4, 128, 1024, 1,
      WqB, W2B, nullptr, Fq, 512, 4, 512,   16, 0,
      WkB, W2B, nullptr, Fk, 512, 4, 512,   16, 0);
  // 3. projections: KH = H1 Fk^T + bk ; QH = H2 Fq^T + bq ; VT2 = Wv Rb^T (= VH^T)
  gemm64<unsigned short><<<dim3(512, 1, 3), 256, 0, stream>>>(
      Hb, Fk, bkf, KHb, 512, 4, 512, 512, 0,
      Hb + (size_t)16384 * 512, Fq, bqf, QHb, 512, 4, 512, 512, 0,
      WvB, Rb, nullptr, VT2, 16384, 128, 512, 512, 0);
  // 4. attention (O aliases QHb: each block writes exactly the rows it read)
  attn_sw<<<dim3(64, 8), 512, 0, stream>>>(QHb, KHb, VT2, Ob);
  // 5. output projection -> f32
  gemm64<float><<<dim3(512, 1, 1), 256, 0, stream>>>(
      Ob, WoT, nullptr, (float*)d_out, 512, 4, 512, 512, 0,
      Ob, WoT, nullptr, (float*)d_out, 512, 4, 512, 512, 0,
      Ob, WoT, nullptr, (float*)d_out, 512, 4, 512, 512, 0);
}